// Round 11
// baseline (7553.101 us; speedup 1.0000x reference)
//
#include <hip/hip_runtime.h>
#include <hip/hip_fp16.h>
#include <cstdint>
#include <cmath>

typedef _Float16 f16x8 __attribute__((ext_vector_type(8)));
typedef float f32x4 __attribute__((ext_vector_type(4)));

#define MFMA16(A, B, C) __builtin_amdgcn_mfma_f32_16x16x32_f16(A, B, C, 0, 0, 0)
#define LO_SCALE 2048.0f
#define LO_INV   4.8828125e-4f

// ---------------- fp32 tiled GEMM (kept only for the tiny wcomb GEMMs) ------------
#define GBM 128
#define GBN 128
#define GBK 16

template<bool TRANSB>
__global__ __launch_bounds__(256)
void gemm_f32(int M, int N, int K,
              const float* __restrict__ A, long long sA,
              const float* __restrict__ B, long long sB,
              float* __restrict__ Cc, long long sC,
              const float* __restrict__ bias,
              const float* __restrict__ rsA,
              const float* __restrict__ rsB)
{
    const int z = blockIdx.z;
    A  += (size_t)z * (size_t)sA;
    B  += (size_t)z * (size_t)sB;
    Cc += (size_t)z * (size_t)sC;

    const int bm = blockIdx.y * GBM;
    const int bn = blockIdx.x * GBN;
    const int tid = threadIdx.x;
    const int tx = tid & 15;
    const int ty = tid >> 4;

    __shared__ float As[GBK][GBM + 4];
    __shared__ float Bs[GBK][GBN + 4];

    float acc[8][8];
#pragma unroll
    for (int i = 0; i < 8; ++i)
#pragma unroll
        for (int j = 0; j < 8; ++j) acc[i][j] = 0.0f;

    const int lr = tid >> 2;
    const int lk = (tid & 3) << 2;
    const int kb_n = tid >> 5;
    const int nb_n = (tid & 31) << 2;

    float sa0 = 1.f, sa1 = 1.f, sb0 = 1.f, sb1 = 1.f;
    if (rsA) {
        sa0 = rsA[(size_t)z * M + bm + lr];
        sa1 = rsA[(size_t)z * M + bm + lr + 64];
    }
    if (TRANSB && rsB) {
        sb0 = rsB[(size_t)z * N + bn + lr];
        sb1 = rsB[(size_t)z * N + bn + lr + 64];
    }

    float4 pa0, pa1, pb0, pb1;

    auto gload = [&](int kt) {
        const float* pA = A + (size_t)(bm + lr) * K + kt * GBK + lk;
        pa0 = *(const float4*)pA;
        pa1 = *(const float4*)(pA + (size_t)64 * K);
        if (TRANSB) {
            const float* pB = B + (size_t)(bn + lr) * K + kt * GBK + lk;
            pb0 = *(const float4*)pB;
            pb1 = *(const float4*)(pB + (size_t)64 * K);
        } else {
            const float* pB = B + (size_t)(kt * GBK + kb_n) * N + bn + nb_n;
            pb0 = *(const float4*)pB;
            pb1 = *(const float4*)(pB + (size_t)8 * N);
        }
    };
    auto sstore = [&]() {
        As[lk + 0][lr] = pa0.x * sa0; As[lk + 1][lr] = pa0.y * sa0;
        As[lk + 2][lr] = pa0.z * sa0; As[lk + 3][lr] = pa0.w * sa0;
        As[lk + 0][lr + 64] = pa1.x * sa1; As[lk + 1][lr + 64] = pa1.y * sa1;
        As[lk + 2][lr + 64] = pa1.z * sa1; As[lk + 3][lr + 64] = pa1.w * sa1;
        if (TRANSB) {
            Bs[lk + 0][lr] = pb0.x * sb0; Bs[lk + 1][lr] = pb0.y * sb0;
            Bs[lk + 2][lr] = pb0.z * sb0; Bs[lk + 3][lr] = pb0.w * sb0;
            Bs[lk + 0][lr + 64] = pb1.x * sb1; Bs[lk + 1][lr + 64] = pb1.y * sb1;
            Bs[lk + 2][lr + 64] = pb1.z * sb1; Bs[lk + 3][lr + 64] = pb1.w * sb1;
        } else {
            *(float4*)&Bs[kb_n][nb_n]     = pb0;
            *(float4*)&Bs[kb_n + 8][nb_n] = pb1;
        }
    };

    const int nkt = K / GBK;
    gload(0);
    sstore();
    __syncthreads();
    for (int kt = 0; kt < nkt; ++kt) {
        if (kt + 1 < nkt) gload(kt + 1);
#pragma unroll
        for (int k = 0; k < GBK; ++k) {
            float4 a0 = *(const float4*)&As[k][ty * 8];
            float4 a1 = *(const float4*)&As[k][ty * 8 + 4];
            float4 b0 = *(const float4*)&Bs[k][tx * 8];
            float4 b1 = *(const float4*)&Bs[k][tx * 8 + 4];
            float av[8] = {a0.x, a0.y, a0.z, a0.w, a1.x, a1.y, a1.z, a1.w};
            float bv[8] = {b0.x, b0.y, b0.z, b0.w, b1.x, b1.y, b1.z, b1.w};
#pragma unroll
            for (int i = 0; i < 8; ++i)
#pragma unroll
                for (int j = 0; j < 8; ++j)
                    acc[i][j] = fmaf(av[i], bv[j], acc[i][j]);
        }
        __syncthreads();
        if (kt + 1 < nkt) { sstore(); __syncthreads(); }
    }

    float bb[8];
#pragma unroll
    for (int j = 0; j < 8; ++j) bb[j] = bias ? bias[bn + tx * 8 + j] : 0.0f;
#pragma unroll
    for (int i = 0; i < 8; ++i) {
        const int row = bm + ty * 8 + i;
        float* cp = Cc + (size_t)row * N + bn + tx * 8;
        float4 o0 = make_float4(acc[i][0] + bb[0], acc[i][1] + bb[1],
                                acc[i][2] + bb[2], acc[i][3] + bb[3]);
        float4 o1 = make_float4(acc[i][4] + bb[4], acc[i][5] + bb[5],
                                acc[i][6] + bb[6], acc[i][7] + bb[7]);
        *(float4*)cp = o0;
        *(float4*)(cp + 4) = o1;
    }
}

// ---------------- combined GRU input bias: bcomb = bih + Wih @ b_proj --------------
__global__ void bias_combine(const float* __restrict__ Wih, const float* __restrict__ b_proj,
                             const float* __restrict__ bih, float* __restrict__ bcomb)
{
    const int j = blockIdx.x * blockDim.x + threadIdx.x;
    if (j >= 768) return;
    float s = bih[j];
    for (int k = 0; k < 512; ++k) s = fmaf(Wih[(size_t)j * 512 + k], b_proj[k], s);
    bcomb[j] = s;
}

// ---------------- pack W[N=768][K=256] into MFMA fp16-split B-fragments ------------
__global__ __launch_bounds__(256)
void pack_w(const float* __restrict__ W, unsigned short* __restrict__ pack)
{
    const int idx = blockIdx.x * 256 + threadIdx.x;
    if (idx >= 768 * 256) return;
    const int n = idx >> 8;
    const int k = idx & 255;
    const float w = W[idx];
    const __half hi = __float2half(w);
    const __half lo = __float2half((w - __half2float(hi)) * LO_SCALE);
    const int nt = n >> 4;
    const int lane = ((k >> 3) & 3) * 16 + (n & 15);
    const int j = k & 7;
    const int kc = k >> 5;
    const size_t base = ((size_t)(nt * 8 + kc) * 2) * 512 + lane * 8 + j;
    pack[base]       = __half_as_ushort(hi);
    pack[base + 512] = __half_as_ushort(lo);
}

// ---------------- pack W[K][N] (row-major) into MFMA fp16-split fragments ----------
__global__ __launch_bounds__(256)
void pack_bk(const float* __restrict__ W, unsigned short* __restrict__ pack,
             int K, int N)
{
    const int idx = blockIdx.x * 256 + threadIdx.x;
    if (idx >= K * N) return;
    const int k = idx / N;
    const int n = idx - k * N;
    const float w = W[idx];
    const __half hi = __float2half(w);
    const __half lo = __float2half((w - __half2float(hi)) * LO_SCALE);
    const int nt = n >> 4;
    const int kc = k >> 5;
    const int lane = ((k >> 3) & 3) * 16 + (n & 15);
    const int j = k & 7;
    const int KC = K >> 5;
    const size_t base = ((size_t)(nt * KC + kc) * 2) * 512 + lane * 8 + j;
    pack[base]       = __half_as_ushort(hi);
    pack[base + 512] = __half_as_ushort(lo);
}

// ---------------- pack Whh for the scan: wpk[(u*3+g)*1024 + j*4+q] = float4 --------
// value = W[g*256+j][u*16 + q*4 .. +3]. Lane tid=j*4+q reads contiguous float4s ->
// every weight-load instruction is one dense 1KB stream (full 128B-line use).
__global__ __launch_bounds__(256)
void pack_wsc(const float* __restrict__ W, float* __restrict__ wpk)
{
    const int idx = blockIdx.x * 256 + threadIdx.x;
    if (idx >= 768 * 256) return;
    const int row = idx >> 8;          // g*256 + j
    const int k   = idx & 255;
    const int g = row >> 8;
    const int j = row & 255;
    const int u = k >> 4;
    const int q = (k >> 2) & 3;
    const int e = k & 3;
    wpk[(((size_t)(u * 3 + g) * 1024) + (j << 2) + q) * 4 + e] = W[idx];
}

// ---------------- gi GEMM chunk (MFMA fp16-split): t-slice [t0, t0+128) ------------
__global__ __launch_bounds__(512)
void gi_gemm_c(const float* __restrict__ Cm, const unsigned short* __restrict__ pack,
               const float* __restrict__ bcomb, float* __restrict__ gi, int t0)
{
    const int tid = threadIdx.x;
    const int w = tid >> 6, l = tid & 63;
    const int l15 = l & 15, l4 = l >> 4;
    const int bgrp = blockIdx.x >> 1;
    const int half = blockIdx.x & 1;
    const size_t m0 = (size_t)bgrp * 256 + t0 + half * 64;
    const size_t o0 = (size_t)bgrp * 128 + half * 64;

    __shared__ unsigned short alds[2][64 * 256];

    {
        const int row = tid >> 3;
        const int seg = (tid & 7) * 32;
        const float4* src = (const float4*)(Cm + (m0 + row) * 256 + seg);
        const int sw = (row & 7) << 3;
#pragma unroll
        for (int i = 0; i < 8; ++i) {
            float4 v = src[i];
            float vv[4] = {v.x, v.y, v.z, v.w};
#pragma unroll
            for (int e = 0; e < 4; ++e) {
                const float x = vv[e];
                const __half hi = __float2half(x);
                const __half lo = __float2half((x - __half2float(hi)) * LO_SCALE);
                const int ad = (row << 8) + ((seg + i * 4 + e) ^ sw);
                alds[0][ad] = __half_as_ushort(hi);
                alds[1][ad] = __half_as_ushort(lo);
            }
        }
    }
    __syncthreads();

    const int mt = w >> 1, nh = w & 1;
    f32x4 acc[24];
#pragma unroll
    for (int i = 0; i < 24; ++i) acc[i] = (f32x4){0.f, 0.f, 0.f, 0.f};

    const int ar = mt * 16 + l15;
    const int arow = ar << 8;
    const int asw = (ar & 7) << 3;

#pragma unroll
    for (int kc = 0; kc < 8; ++kc) {
        const int ad = arow + ((kc * 32 + l4 * 8) ^ asw);
        const f16x8 ahi = *(const f16x8*)&alds[0][ad];
        const f16x8 alo = *(const f16x8*)&alds[1][ad];
#pragma unroll
        for (int nt = 0; nt < 24; ++nt) {
            const int nt_lin = nh * 24 + nt;
            const uint4* bp = (const uint4*)(pack + ((size_t)(nt_lin * 8 + kc) * 2) * 512);
            uint4 bh4 = bp[l];
            uint4 bl4 = bp[64 + l];
            const f16x8 Bhi = *reinterpret_cast<const f16x8*>(&bh4);
            const f16x8 Blo = *reinterpret_cast<const f16x8*>(&bl4);
            acc[nt] = MFMA16(ahi, Bhi, acc[nt]);
            f32x4 t2 = (f32x4){0.f, 0.f, 0.f, 0.f};
            t2 = MFMA16(ahi, Blo, t2);
            t2 = MFMA16(alo, Bhi, t2);
#pragma unroll
            for (int r = 0; r < 4; ++r) acc[nt][r] = fmaf(LO_INV, t2[r], acc[nt][r]);
        }
    }

#pragma unroll
    for (int nt = 0; nt < 24; ++nt) {
        const int n = (nh * 24 + nt) * 16 + l15;
        const float bb = bcomb[n];
#pragma unroll
        for (int r = 0; r < 4; ++r) {
            const size_t om = o0 + mt * 16 + l4 * 4 + r;
            __builtin_nontemporal_store(acc[nt][r] + bb, &gi[om * 768 + n]);
        }
    }
}

// ---------------- GRU scan v12: G=8, 64 blocks (L2-resident weights, half HBM
// traffic), coalesced packed weights, gi register pipeline, explicit 2-u-chunk
// register double buffer for weights (statically indexed). Thread (j=tid>>2,
// q=tid&3): Whh rows {j,j+256,j+512}, k-slice {u*16+q*4}, partial dots for all
// 8 batches; xor-1,2 reduce; lane q activates batches q and q+4.
__global__ __launch_bounds__(1024, 4)
void gru_scan_v12(const float* __restrict__ gi_fc, const float* __restrict__ gi_bc,
                  const float* __restrict__ wpk_f, const float* __restrict__ wpk_b,
                  const float* __restrict__ bhh_f, const float* __restrict__ bhh_b,
                  float* __restrict__ H, float* __restrict__ hstate, int phase)
{
    const int bid = blockIdx.x;                   // 0..63
    const int xcd = bid & 7;
    const int dir = xcd >> 2;
    const int grp = (bid >> 3) * 4 + (xcd & 3);   // 0..31
    const float* __restrict__ gi  = dir ? gi_bc : gi_fc;
    const float4* __restrict__ Wp = (const float4*)(dir ? wpk_b : wpk_f);
    const float* __restrict__ bhh = dir ? bhh_b : bhh_f;
    const int b0 = grp * 8;
    const int t0 = dir ? (128 - phase * 128) : (phase * 128);

    const int tid = threadIdx.x;
    const int j = tid >> 2;    // unit 0..255
    const int q = tid & 3;     // k-quarter; owns batches q and q+4
    const int bA = q, bB = q + 4;

    __shared__ float hb[2][8][256];

    float hregA, hregB;
    if (phase == 0) { hregA = 0.f; hregB = 0.f; }
    else {
        hregA = hstate[((size_t)dir * 256 + b0 + bA) * 256 + j];
        hregB = hstate[((size_t)dir * 256 + b0 + bB) * 256 + j];
    }
    hb[0][bA][j] = hregA;
    hb[0][bB][j] = hregB;

    const float bh_r = bhh[j], bh_z = bhh[j + 256], bh_n = bhh[j + 512];

    __syncthreads();

    // gi software pipeline: prefetch step 0 for both owned batches
    const int sc00 = dir ? 127 : 0;
    const float* gA0 = gi + ((size_t)(b0 + bA) * 128 + sc00) * 768 + j;
    const float* gB0 = gi + ((size_t)(b0 + bB) * 128 + sc00) * 768 + j;
    float grA = __builtin_nontemporal_load(gA0);
    float gzA = __builtin_nontemporal_load(gA0 + 256);
    float gnA = __builtin_nontemporal_load(gA0 + 512);
    float grB = __builtin_nontemporal_load(gB0);
    float gzB = __builtin_nontemporal_load(gB0 + 256);
    float gnB = __builtin_nontemporal_load(gB0 + 512);

    int p = 0;
    for (int tau = 0; tau < 128; ++tau) {
        const int sc = dir ? (127 - tau) : tau;
        const int tt = t0 + sc;

        const float g_rA = grA, g_zA = gzA, g_nA = gnA;
        const float g_rB = grB, g_zB = gzB, g_nB = gnB;
        if (tau < 127) {   // prefetch next step's gi
            const int scn = dir ? (126 - tau) : (tau + 1);
            const float* gA = gi + ((size_t)(b0 + bA) * 128 + scn) * 768 + j;
            const float* gB = gi + ((size_t)(b0 + bB) * 128 + scn) * 768 + j;
            grA = __builtin_nontemporal_load(gA);
            gzA = __builtin_nontemporal_load(gA + 256);
            gnA = __builtin_nontemporal_load(gA + 512);
            grB = __builtin_nontemporal_load(gB);
            gzB = __builtin_nontemporal_load(gB + 256);
            gnB = __builtin_nontemporal_load(gB + 512);
        }

        float ar[8], az[8], an[8];
#pragma unroll
        for (int b = 0; b < 8; ++b) { ar[b] = 0.f; az[b] = 0.f; an[b] = 0.f; }

        // explicit register double buffer: chunks of 2 u (6 float4 per chunk)
        float4 wb0[6], wb1[6];
#pragma unroll
        for (int s = 0; s < 2; ++s) {
            wb0[s * 3 + 0] = Wp[((s) * 3 + 0) * 1024 + tid];
            wb0[s * 3 + 1] = Wp[((s) * 3 + 1) * 1024 + tid];
            wb0[s * 3 + 2] = Wp[((s) * 3 + 2) * 1024 + tid];
        }

#pragma unroll
        for (int c = 0; c < 8; ++c) {
            // issue next chunk's loads into the other buffer
            if (c < 7) {
#pragma unroll
                for (int s = 0; s < 2; ++s) {
                    const int uu = (c + 1) * 2 + s;
                    if (c & 1) {
                        wb0[s * 3 + 0] = Wp[(uu * 3 + 0) * 1024 + tid];
                        wb0[s * 3 + 1] = Wp[(uu * 3 + 1) * 1024 + tid];
                        wb0[s * 3 + 2] = Wp[(uu * 3 + 2) * 1024 + tid];
                    } else {
                        wb1[s * 3 + 0] = Wp[(uu * 3 + 0) * 1024 + tid];
                        wb1[s * 3 + 1] = Wp[(uu * 3 + 1) * 1024 + tid];
                        wb1[s * 3 + 2] = Wp[(uu * 3 + 2) * 1024 + tid];
                    }
                }
            }
            // consume current chunk (buffer selected statically by c&1)
#pragma unroll
            for (int s = 0; s < 2; ++s) {
                const int u = c * 2 + s;
                const float4 wr = (c & 1) ? wb1[s * 3 + 0] : wb0[s * 3 + 0];
                const float4 wz = (c & 1) ? wb1[s * 3 + 1] : wb0[s * 3 + 1];
                const float4 wn = (c & 1) ? wb1[s * 3 + 2] : wb0[s * 3 + 2];
                const int ha = u * 16 + q * 4;
#pragma unroll
                for (int b = 0; b < 8; ++b) {
                    const float4 hv = *(const float4*)&hb[p][b][ha];
                    ar[b] = fmaf(wr.x, hv.x, ar[b]); ar[b] = fmaf(wr.y, hv.y, ar[b]);
                    ar[b] = fmaf(wr.z, hv.z, ar[b]); ar[b] = fmaf(wr.w, hv.w, ar[b]);
                    az[b] = fmaf(wz.x, hv.x, az[b]); az[b] = fmaf(wz.y, hv.y, az[b]);
                    az[b] = fmaf(wz.z, hv.z, az[b]); az[b] = fmaf(wz.w, hv.w, az[b]);
                    an[b] = fmaf(wn.x, hv.x, an[b]); an[b] = fmaf(wn.y, hv.y, an[b]);
                    an[b] = fmaf(wn.z, hv.z, an[b]); an[b] = fmaf(wn.w, hv.w, an[b]);
                }
            }
        }

#pragma unroll
        for (int b = 0; b < 8; ++b) {
            ar[b] += __shfl_xor(ar[b], 1); ar[b] += __shfl_xor(ar[b], 2);
            az[b] += __shfl_xor(az[b], 1); az[b] += __shfl_xor(az[b], 2);
            an[b] += __shfl_xor(an[b], 1); an[b] += __shfl_xor(an[b], 2);
        }

        // static selects (no runtime register indexing)
        const float prA = (q == 0) ? ar[0] : (q == 1) ? ar[1] : (q == 2) ? ar[2] : ar[3];
        const float pzA = (q == 0) ? az[0] : (q == 1) ? az[1] : (q == 2) ? az[2] : az[3];
        const float pnA = (q == 0) ? an[0] : (q == 1) ? an[1] : (q == 2) ? an[2] : an[3];
        const float prB = (q == 0) ? ar[4] : (q == 1) ? ar[5] : (q == 2) ? ar[6] : ar[7];
        const float pzB = (q == 0) ? az[4] : (q == 1) ? az[5] : (q == 2) ? az[6] : az[7];
        const float pnB = (q == 0) ? an[4] : (q == 1) ? an[5] : (q == 2) ? an[6] : an[7];

        float rr = 1.0f / (1.0f + expf(-(g_rA + prA + bh_r)));
        float zz = 1.0f / (1.0f + expf(-(g_zA + pzA + bh_z)));
        float nn = tanhf(g_nA + rr * (pnA + bh_n));
        hregA = (1.0f - zz) * nn + zz * hregA;
        rr = 1.0f / (1.0f + expf(-(g_rB + prB + bh_r)));
        zz = 1.0f / (1.0f + expf(-(g_zB + pzB + bh_z)));
        nn = tanhf(g_nB + rr * (pnB + bh_n));
        hregB = (1.0f - zz) * nn + zz * hregB;

        hb[p ^ 1][bA][j] = hregA;
        hb[p ^ 1][bB][j] = hregB;
        __builtin_nontemporal_store(
            hregA, &H[((size_t)(b0 + bA) * 256 + tt) * 512 + dir * 256 + j]);
        __builtin_nontemporal_store(
            hregB, &H[((size_t)(b0 + bB) * 256 + tt) * 512 + dir * 256 + j]);
        __syncthreads();
        p ^= 1;
    }

    hstate[((size_t)dir * 256 + b0 + bA) * 256 + j] = hregA;
    hstate[((size_t)dir * 256 + b0 + bB) * 256 + j] = hregB;
}

// ---------------- row 1/max(norm,1e-12) for cosine normalization ------------------
__global__ __launch_bounds__(256)
void rownorm(const float* __restrict__ H, float* __restrict__ rinv)
{
    const int row  = blockIdx.x * 4 + (threadIdx.x >> 6);
    const int lane = threadIdx.x & 63;
    const float4* p = (const float4*)(H + (size_t)row * 512);
    float ss = 0.f;
    float4 v = p[lane];
    ss += v.x * v.x + v.y * v.y + v.z * v.z + v.w * v.w;
    v = p[lane + 64];
    ss += v.x * v.x + v.y * v.y + v.z * v.z + v.w * v.w;
#pragma unroll
    for (int off = 32; off >= 1; off >>= 1) ss += __shfl_xor(ss, off);
    if (lane == 0) rinv[row] = 1.0f / fmaxf(sqrtf(ss), 1e-12f);
}

// ---------------- sim (MFMA fp16-split, batched 256x256x512, rinv folded) ----------
__global__ __launch_bounds__(512)
void sim_mfma(const float* __restrict__ H, const float* __restrict__ rinv,
              float* __restrict__ sim)
{
    const int b = blockIdx.x;
    const int tid = threadIdx.x;
    const int w = tid >> 6, l = tid & 63;
    const int l15 = l & 15, l4 = l >> 4;

    __shared__ unsigned short st[2][256][40];

    f32x4 acc[2][16];
#pragma unroll
    for (int m = 0; m < 2; ++m)
#pragma unroll
        for (int n = 0; n < 16; ++n) acc[m][n] = (f32x4){0.f, 0.f, 0.f, 0.f};

    const int sr = tid >> 1;
    const int sh = (tid & 1) * 16;
    const float rv = rinv[b * 256 + sr];
    const float* hrow = H + ((size_t)b * 256 + sr) * 512;

    for (int kc = 0; kc < 16; ++kc) {
        if (kc) __syncthreads();
        {
            const float4* src = (const float4*)(hrow + kc * 32 + sh);
#pragma unroll
            for (int i = 0; i < 4; ++i) {
                float4 v = src[i];
                float vv[4] = {v.x, v.y, v.z, v.w};
                ushort4 h4, l4v;
                unsigned short* hp = (unsigned short*)&h4;
                unsigned short* lp = (unsigned short*)&l4v;
#pragma unroll
                for (int e = 0; e < 4; ++e) {
                    const float x = vv[e] * rv;
                    const __half hi = __float2half(x);
                    const __half lo = __float2half((x - __half2float(hi)) * LO_SCALE);
                    hp[e] = __half_as_ushort(hi);
                    lp[e] = __half_as_ushort(lo);
                }
                *(ushort4*)&st[0][sr][sh + i * 4] = h4;
                *(ushort4*)&st[1][sr][sh + i * 4] = l4v;
            }
        }
        __syncthreads();

        f16x8 ahi[2], alo[2];
#pragma unroll
        for (int m = 0; m < 2; ++m) {
            const int row = (w * 2 + m) * 16 + l15;
            ahi[m] = *(const f16x8*)&st[0][row][l4 * 8];
            alo[m] = *(const f16x8*)&st[1][row][l4 * 8];
        }
#pragma unroll
        for (int nt = 0; nt < 16; ++nt) {
            const int col = nt * 16 + l15;
            const f16x8 bhi = *(const f16x8*)&st[0][col][l4 * 8];
            const f16x8 blo = *(const f16x8*)&st[1][col][l4 * 8];
#pragma unroll
            for (int m = 0; m < 2; ++m) {
                acc[m][nt] = MFMA16(ahi[m], bhi, acc[m][nt]);
                f32x4 t2 = (f32x4){0.f, 0.f, 0.f, 0.f};
                t2 = MFMA16(ahi[m], blo, t2);
                t2 = MFMA16(alo[m], bhi, t2);
#pragma unroll
                for (int r = 0; r < 4; ++r)
                    acc[m][nt][r] = fmaf(LO_INV, t2[r], acc[m][nt][r]);
            }
        }
    }

#pragma unroll
    for (int m = 0; m < 2; ++m) {
        const int row0 = (w * 2 + m) * 16 + l4 * 4;
#pragma unroll
        for (int nt = 0; nt < 16; ++nt)
#pragma unroll
            for (int r = 0; r < 4; ++r)
                sim[((size_t)b * 256 + row0 + r) * 256 + nt * 16 + l15] = acc[m][nt][r];
    }
}

// ---------------- GCN layer GEMMs (MFMA fp16-split), A staged from fp32 ------------
template<int KDIM, int NDIM, int NT_PER>
__global__ __launch_bounds__(512)
void gcn_mm(const float* __restrict__ X, const unsigned short* __restrict__ pack,
            float* __restrict__ Y)
{
    const int tid = threadIdx.x;
    const int w = tid >> 6, l = tid & 63;
    const int l15 = l & 15, l4 = l >> 4;
    const int m0 = blockIdx.x * 64;
    constexpr int KC = KDIM / 32;

    __shared__ unsigned short a[2][64 * KDIM];

    {
        const int row = tid >> 3;
        const int seg = (tid & 7) * (KDIM / 8);
        const float4* src = (const float4*)(X + (size_t)(m0 + row) * KDIM + seg);
        const int sw = (row & 7) << 3;
#pragma unroll
        for (int i = 0; i < KDIM / 32; ++i) {
            float4 v = src[i];
            float vv[4] = {v.x, v.y, v.z, v.w};
#pragma unroll
            for (int e = 0; e < 4; ++e) {
                const float x = vv[e];
                const __half hi = __float2half(x);
                const __half lo = __float2half((x - __half2float(hi)) * LO_SCALE);
                const int ad = row * KDIM + ((seg + i * 4 + e) ^ sw);
                a[0][ad] = __half_as_ushort(hi);
                a[1][ad] = __half_as_ushort(lo);
            }
        }
    }
    __syncthreads();

    const int mt = w >> 1, nh = w & 1;
    f32x4 acc[NT_PER];
#pragma unroll
    for (int i = 0; i < NT_PER; ++i) acc[i] = (f32x4){0.f, 0.f, 0.f, 0.f};

    const int arow = mt * 16 + l15;
    const int abase = arow * KDIM;
    const int asw = (arow & 7) << 3;

#pragma unroll
    for (int kc = 0; kc < KC; ++kc) {
        const int ad = abase + ((kc * 32 + l4 * 8) ^ asw);
        const f16x8 ahi = *(const f16x8*)&a[0][ad];
        const f16x8 alo = *(const f16x8*)&a[1][ad];
#pragma unroll
        for (int ntl = 0; ntl < NT_PER; ++ntl) {
            const int nt = nh * NT_PER + ntl;
            const uint4* bp = (const uint4*)(pack + ((size_t)(nt * KC + kc) * 2) * 512);
            uint4 bh4 = bp[l];
            uint4 bl4 = bp[64 + l];
            const f16x8 Bhi = *reinterpret_cast<const f16x8*>(&bh4);
            const f16x8 Blo = *reinterpret_cast<const f16x8*>(&bl4);
            acc[ntl] = MFMA16(ahi, Bhi, acc[ntl]);
            f32x4 t2 = (f32x4){0.f, 0.f, 0.f, 0.f};
            t2 = MFMA16(ahi, Blo, t2);
            t2 = MFMA16(alo, Bhi, t2);
#pragma unroll
            for (int r = 0; r < 4; ++r) acc[ntl][r] = fmaf(LO_INV, t2[r], acc[ntl][r]);
        }
    }

#pragma unroll
    for (int ntl = 0; ntl < NT_PER; ++ntl) {
        const int n = (nh * NT_PER + ntl) * 16 + l15;
#pragma unroll
        for (int r = 0; r < 4; ++r) {
            const int m = m0 + mt * 16 + l4 * 4 + r;
            Y[(size_t)m * NDIM + n] = acc[ntl][r];
        }
    }
}

// ---------------- top-5 per sim row (strict >, jax lower-index tie behavior) ------
__global__ __launch_bounds__(256)
void topk5(const float* __restrict__ sim, int* __restrict__ idx)
{
    const int row = blockIdx.x * 256 + threadIdx.x;
    const float* p = sim + (size_t)row * 256;
    float bv0 = -1e30f, bv1 = -1e30f, bv2 = -1e30f, bv3 = -1e30f, bv4 = -1e30f;
    int   bi0 = 0, bi1 = 0, bi2 = 0, bi3 = 0, bi4 = 0;
    for (int m4 = 0; m4 < 64; ++m4) {
        float4 v4 = *(const float4*)(p + m4 * 4);
        float vv[4] = {v4.x, v4.y, v4.z, v4.w};
#pragma unroll
        for (int c = 0; c < 4; ++c) {
            float v = vv[c];
            int   m = m4 * 4 + c;
            if (v > bv0) {
                if (v > bv1) {
                    bv0 = bv1; bi0 = bi1;
                    if (v > bv2) {
                        bv1 = bv2; bi1 = bi2;
                        if (v > bv3) {
                            bv2 = bv3; bi2 = bi3;
                            if (v > bv4) { bv3 = bv4; bi3 = bi4; bv4 = v; bi4 = m; }
                            else         { bv3 = v;  bi3 = m; }
                        } else { bv2 = v; bi2 = m; }
                    } else { bv1 = v; bi1 = m; }
                } else { bv0 = v; bi0 = m; }
            }
        }
    }
    int* o = idx + (size_t)row * 5;
    o[0] = bi0; o[1] = bi1; o[2] = bi2; o[3] = bi3; o[4] = bi4;
}

// ---------------- sparse GCN aggregation: out[n] = c*(X[n] + sum_j X[idx_j]) ------
template<bool RELU, int DIM>
__global__ __launch_bounds__(128)
void gcn_agg(const float* __restrict__ X, const int* __restrict__ idxs,
             float* __restrict__ outp, float cnorm)
{
    const int row = blockIdx.x;
    const int bbase = row & ~255;
    const int* id = idxs + (size_t)row * 5;
    const int i0 = bbase + id[0];
    const int i1 = bbase + id[1];
    const int i2 = bbase + id[2];
    const int i3 = bbase + id[3];
    const int i4 = bbase + id[4];
    const int t = threadIdx.x;
    if (DIM == 512) {
        const float4* Xp = (const float4*)X;
        float4 a = Xp[(size_t)row * 128 + t];
        float4 v;
        v = Xp[(size_t)i0 * 128 + t]; a.x += v.x; a.y += v.y; a.z += v.z; a.w += v.w;
        v = Xp[(size_t)i1 * 128 + t]; a.x += v.x; a.y += v.y; a.z += v.z; a.w += v.w;
        v = Xp[(size_t)i2 * 128 + t]; a.x += v.x; a.y += v.y; a.z += v.z; a.w += v.w;
        v = Xp[(size_t)i3 * 128 + t]; a.x += v.x; a.y += v.y; a.z += v.z; a.w += v.w;
        v = Xp[(size_t)i4 * 128 + t]; a.x += v.x; a.y += v.y; a.z += v.z; a.w += v.w;
        a.x *= cnorm; a.y *= cnorm; a.z *= cnorm; a.w *= cnorm;
        if (RELU) {
            a.x = fmaxf(a.x, 0.f); a.y = fmaxf(a.y, 0.f);
            a.z = fmaxf(a.z, 0.f); a.w = fmaxf(a.w, 0.f);
        }
        ((float4*)outp)[(size_t)row * 128 + t] = a;
    } else {
        float a = X[(size_t)row * 128 + t];
        a += X[(size_t)i0 * 128 + t];
        a += X[(size_t)i1 * 128 + t];
        a += X[(size_t)i2 * 128 + t];
        a += X[(size_t)i3 * 128 + t];
        a += X[(size_t)i4 * 128 + t];
        a *= cnorm;
        if (RELU) a = fmaxf(a, 0.f);
        outp[(size_t)row * 128 + t] = a;
    }
}

// ------------------------------- launcher -----------------------------------------
extern "C" void kernel_launch(void* const* d_in, const int* in_sizes, int n_in,
                              void* d_out, int out_size, void* d_ws, size_t ws_size,
                              hipStream_t stream)
{
    (void)in_sizes; (void)n_in; (void)out_size; (void)ws_size;

    const float* C_masked = (const float*)d_in[0];
    const float* W_proj   = (const float*)d_in[1];
    const float* b_proj   = (const float*)d_in[2];
    const float* Wih_f    = (const float*)d_in[3];
    const float* Whh_f    = (const float*)d_in[4];
    const float* bih_f    = (const float*)d_in[5];
    const float* bhh_f    = (const float*)d_in[6];
    const float* Wih_b    = (const float*)d_in[7];
    const float* Whh_b    = (const float*)d_in[8];
    const float* bih_b    = (const float*)d_in[9];
    const float* bhh_b    = (const float*)d_in[10];
    const float* W_gcn1   = (const float*)d_in[11];
    const float* W_gcn2   = (const float*)d_in[12];
    float* out = (float*)d_out;

    char* ws = (char*)d_ws;
    size_t o = 0;
    auto take = [&](size_t bytes) {
        size_t r = o;
        o = (o + bytes + 255) & ~(size_t)255;
        return r;
    };
    const size_t WCOMB_B = (size_t)768 * 256 * 4;
    const size_t PACK_B  = (size_t)48 * 8 * 2 * 512 * 2;   // 786432
    const size_t PACKG_B = (size_t)262144;
    const size_t o_wcf  = take(WCOMB_B);
    const size_t o_wcb  = take(WCOMB_B);
    const size_t o_bcf  = take(768 * 4);
    const size_t o_bcb  = take(768 * 4);
    const size_t o_rinv = take((size_t)65536 * 4);
    const size_t o_topk = take((size_t)65536 * 5 * 4);
    const size_t o_pwf  = take(PACK_B);
    const size_t o_pwb  = take(PACK_B);
    const size_t o_wsf  = take(WCOMB_B);                   // scan weights fwd (packed)
    const size_t o_wsb  = take(WCOMB_B);                   // scan weights bwd (packed)
    const size_t o_pg1  = take(PACKG_B);
    const size_t o_pg2  = take(PACKG_B);
    const size_t o_hst  = take((size_t)512 * 256 * 4);     // h checkpoint (512 KB)
    const size_t regionA = o;

    const size_t GIC_BYTES = (size_t)256 * 128 * 768 * 4;  // 100.7 MB per dir
    // peak: regionA + 2*GIC + H ~= 343 MB

    float* wcomb_f = (float*)(ws + o_wcf);
    float* wcomb_b = (float*)(ws + o_wcb);
    float* bcomb_f = (float*)(ws + o_bcf);
    float* bcomb_b = (float*)(ws + o_bcb);
    float* rinv    = (float*)(ws + o_rinv);
    int*   topk    = (int*)(ws + o_topk);
    unsigned short* packWf = (unsigned short*)(ws + o_pwf);
    unsigned short* packWb = (unsigned short*)(ws + o_pwb);
    float* wpkF = (float*)(ws + o_wsf);
    float* wpkB = (float*)(ws + o_wsb);
    unsigned short* packG1 = (unsigned short*)(ws + o_pg1);
    unsigned short* packG2 = (unsigned short*)(ws + o_pg2);
    float* hstate = (float*)(ws + o_hst);

    float* gi_fc = (float*)(ws + regionA);
    float* gi_bc = (float*)(ws + regionA + GIC_BYTES);
    float* Hbuf  = (float*)(ws + regionA + 2 * GIC_BYTES);

    float* sim  = (float*)(ws + regionA);               // 67.1 MB
    float* XW1  = (float*)(ws + regionA + 67108864);    // 33.6 MB
    float* Z1   = (float*)(ws + regionA + 100663296);   // 33.6 MB
    float* Z1W2 = (float*)(ws + regionA);               // 134.2 MB

    const dim3 blk(256);

    // 1. combined weights + biases; packs
    gemm_f32<false><<<dim3(2, 6, 1), blk, 0, stream>>>(
        768, 256, 512, Wih_f, 0, W_proj, 0, wcomb_f, 0, nullptr, nullptr, nullptr);
    gemm_f32<false><<<dim3(2, 6, 1), blk, 0, stream>>>(
        768, 256, 512, Wih_b, 0, W_proj, 0, wcomb_b, 0, nullptr, nullptr, nullptr);
    bias_combine<<<3, 256, 0, stream>>>(Wih_f, b_proj, bih_f, bcomb_f);
    bias_combine<<<3, 256, 0, stream>>>(Wih_b, b_proj, bih_b, bcomb_b);
    pack_w<<<768, 256, 0, stream>>>(wcomb_f, packWf);
    pack_w<<<768, 256, 0, stream>>>(wcomb_b, packWb);
    pack_wsc<<<768, 256, 0, stream>>>(Whh_f, wpkF);
    pack_wsc<<<768, 256, 0, stream>>>(Whh_b, wpkB);
    pack_bk<<<256, 256, 0, stream>>>(W_gcn1, packG1, 512, 128);
    pack_bk<<<256, 256, 0, stream>>>(W_gcn2, packG2, 128, 512);

    // 2. time-chunked gi + bidirectional parallel scan (2 phases x 128 steps)
    gi_gemm_c<<<512, 512, 0, stream>>>(C_masked, packWf, bcomb_f, gi_fc, 0);
    gi_gemm_c<<<512, 512, 0, stream>>>(C_masked, packWb, bcomb_b, gi_bc, 128);
    gru_scan_v12<<<64, 1024, 0, stream>>>(gi_fc, gi_bc, wpkF, wpkB,
                                          bhh_f, bhh_b, Hbuf, hstate, 0);
    gi_gemm_c<<<512, 512, 0, stream>>>(C_masked, packWf, bcomb_f, gi_fc, 128);
    gi_gemm_c<<<512, 512, 0, stream>>>(C_masked, packWb, bcomb_b, gi_bc, 0);
    gru_scan_v12<<<64, 1024, 0, stream>>>(gi_fc, gi_bc, wpkF, wpkB,
                                          bhh_f, bhh_b, Hbuf, hstate, 1);

    // 3. cosine-sim (MFMA, rinv folded) -> top-5
    rownorm<<<16384, blk, 0, stream>>>(Hbuf, rinv);
    sim_mfma<<<256, 512, 0, stream>>>(Hbuf, rinv, sim);
    topk5<<<256, blk, 0, stream>>>(sim, topk);

    // 4. GCN with A_norm = A / (6 + 1e-8)  (row-sum of A is always K+1 = 6)
    const float cnorm = (float)(1.0 / (6.0 + 1e-8));
    gcn_mm<512, 128, 4><<<1024, 512, 0, stream>>>(Hbuf, packG1, XW1);
    gcn_agg<true, 128><<<65536, 128, 0, stream>>>(XW1, topk, Z1, cnorm);
    gcn_mm<128, 512, 16><<<1024, 512, 0, stream>>>(Z1, packG2, Z1W2);
    gcn_agg<false, 512><<<65536, 128, 0, stream>>>(Z1W2, topk, out, cnorm);
}

// Round 12
// 5702.774 us; speedup vs baseline: 1.3245x; 1.3245x over previous
//
#include <hip/hip_runtime.h>
#include <hip/hip_fp16.h>
#include <cstdint>
#include <cmath>

typedef _Float16 f16x8 __attribute__((ext_vector_type(8)));
typedef float f32x4 __attribute__((ext_vector_type(4)));

#define MFMA16(A, B, C) __builtin_amdgcn_mfma_f32_16x16x32_f16(A, B, C, 0, 0, 0)
#define LO_SCALE 2048.0f
#define LO_INV   4.8828125e-4f

// ---------------- fp32 tiled GEMM (kept only for the tiny wcomb GEMMs) ------------
#define GBM 128
#define GBN 128
#define GBK 16

template<bool TRANSB>
__global__ __launch_bounds__(256)
void gemm_f32(int M, int N, int K,
              const float* __restrict__ A, long long sA,
              const float* __restrict__ B, long long sB,
              float* __restrict__ Cc, long long sC,
              const float* __restrict__ bias,
              const float* __restrict__ rsA,
              const float* __restrict__ rsB)
{
    const int z = blockIdx.z;
    A  += (size_t)z * (size_t)sA;
    B  += (size_t)z * (size_t)sB;
    Cc += (size_t)z * (size_t)sC;

    const int bm = blockIdx.y * GBM;
    const int bn = blockIdx.x * GBN;
    const int tid = threadIdx.x;
    const int tx = tid & 15;
    const int ty = tid >> 4;

    __shared__ float As[GBK][GBM + 4];
    __shared__ float Bs[GBK][GBN + 4];

    float acc[8][8];
#pragma unroll
    for (int i = 0; i < 8; ++i)
#pragma unroll
        for (int j = 0; j < 8; ++j) acc[i][j] = 0.0f;

    const int lr = tid >> 2;
    const int lk = (tid & 3) << 2;
    const int kb_n = tid >> 5;
    const int nb_n = (tid & 31) << 2;

    float sa0 = 1.f, sa1 = 1.f, sb0 = 1.f, sb1 = 1.f;
    if (rsA) {
        sa0 = rsA[(size_t)z * M + bm + lr];
        sa1 = rsA[(size_t)z * M + bm + lr + 64];
    }
    if (TRANSB && rsB) {
        sb0 = rsB[(size_t)z * N + bn + lr];
        sb1 = rsB[(size_t)z * N + bn + lr + 64];
    }

    float4 pa0, pa1, pb0, pb1;

    auto gload = [&](int kt) {
        const float* pA = A + (size_t)(bm + lr) * K + kt * GBK + lk;
        pa0 = *(const float4*)pA;
        pa1 = *(const float4*)(pA + (size_t)64 * K);
        if (TRANSB) {
            const float* pB = B + (size_t)(bn + lr) * K + kt * GBK + lk;
            pb0 = *(const float4*)pB;
            pb1 = *(const float4*)(pB + (size_t)64 * K);
        } else {
            const float* pB = B + (size_t)(kt * GBK + kb_n) * N + bn + nb_n;
            pb0 = *(const float4*)pB;
            pb1 = *(const float4*)(pB + (size_t)8 * N);
        }
    };
    auto sstore = [&]() {
        As[lk + 0][lr] = pa0.x * sa0; As[lk + 1][lr] = pa0.y * sa0;
        As[lk + 2][lr] = pa0.z * sa0; As[lk + 3][lr] = pa0.w * sa0;
        As[lk + 0][lr + 64] = pa1.x * sa1; As[lk + 1][lr + 64] = pa1.y * sa1;
        As[lk + 2][lr + 64] = pa1.z * sa1; As[lk + 3][lr + 64] = pa1.w * sa1;
        if (TRANSB) {
            Bs[lk + 0][lr] = pb0.x * sb0; Bs[lk + 1][lr] = pb0.y * sb0;
            Bs[lk + 2][lr] = pb0.z * sb0; Bs[lk + 3][lr] = pb0.w * sb0;
            Bs[lk + 0][lr + 64] = pb1.x * sb1; Bs[lk + 1][lr + 64] = pb1.y * sb1;
            Bs[lk + 2][lr + 64] = pb1.z * sb1; Bs[lk + 3][lr + 64] = pb1.w * sb1;
        } else {
            *(float4*)&Bs[kb_n][nb_n]     = pb0;
            *(float4*)&Bs[kb_n + 8][nb_n] = pb1;
        }
    };

    const int nkt = K / GBK;
    gload(0);
    sstore();
    __syncthreads();
    for (int kt = 0; kt < nkt; ++kt) {
        if (kt + 1 < nkt) gload(kt + 1);
#pragma unroll
        for (int k = 0; k < GBK; ++k) {
            float4 a0 = *(const float4*)&As[k][ty * 8];
            float4 a1 = *(const float4*)&As[k][ty * 8 + 4];
            float4 b0 = *(const float4*)&Bs[k][tx * 8];
            float4 b1 = *(const float4*)&Bs[k][tx * 8 + 4];
            float av[8] = {a0.x, a0.y, a0.z, a0.w, a1.x, a1.y, a1.z, a1.w};
            float bv[8] = {b0.x, b0.y, b0.z, b0.w, b1.x, b1.y, b1.z, b1.w};
#pragma unroll
            for (int i = 0; i < 8; ++i)
#pragma unroll
                for (int j = 0; j < 8; ++j)
                    acc[i][j] = fmaf(av[i], bv[j], acc[i][j]);
        }
        __syncthreads();
        if (kt + 1 < nkt) { sstore(); __syncthreads(); }
    }

    float bb[8];
#pragma unroll
    for (int j = 0; j < 8; ++j) bb[j] = bias ? bias[bn + tx * 8 + j] : 0.0f;
#pragma unroll
    for (int i = 0; i < 8; ++i) {
        const int row = bm + ty * 8 + i;
        float* cp = Cc + (size_t)row * N + bn + tx * 8;
        float4 o0 = make_float4(acc[i][0] + bb[0], acc[i][1] + bb[1],
                                acc[i][2] + bb[2], acc[i][3] + bb[3]);
        float4 o1 = make_float4(acc[i][4] + bb[4], acc[i][5] + bb[5],
                                acc[i][6] + bb[6], acc[i][7] + bb[7]);
        *(float4*)cp = o0;
        *(float4*)(cp + 4) = o1;
    }
}

// ---------------- combined GRU input bias: bcomb = bih + Wih @ b_proj --------------
__global__ void bias_combine(const float* __restrict__ Wih, const float* __restrict__ b_proj,
                             const float* __restrict__ bih, float* __restrict__ bcomb)
{
    const int j = blockIdx.x * blockDim.x + threadIdx.x;
    if (j >= 768) return;
    float s = bih[j];
    for (int k = 0; k < 512; ++k) s = fmaf(Wih[(size_t)j * 512 + k], b_proj[k], s);
    bcomb[j] = s;
}

// ---------------- pack W[N=768][K=256] into MFMA fp16-split B-fragments ------------
__global__ __launch_bounds__(256)
void pack_w(const float* __restrict__ W, unsigned short* __restrict__ pack)
{
    const int idx = blockIdx.x * 256 + threadIdx.x;
    if (idx >= 768 * 256) return;
    const int n = idx >> 8;
    const int k = idx & 255;
    const float w = W[idx];
    const __half hi = __float2half(w);
    const __half lo = __float2half((w - __half2float(hi)) * LO_SCALE);
    const int nt = n >> 4;
    const int lane = ((k >> 3) & 3) * 16 + (n & 15);
    const int j = k & 7;
    const int kc = k >> 5;
    const size_t base = ((size_t)(nt * 8 + kc) * 2) * 512 + lane * 8 + j;
    pack[base]       = __half_as_ushort(hi);
    pack[base + 512] = __half_as_ushort(lo);
}

// ---------------- pack W[K][N] (row-major) into MFMA fp16-split fragments ----------
__global__ __launch_bounds__(256)
void pack_bk(const float* __restrict__ W, unsigned short* __restrict__ pack,
             int K, int N)
{
    const int idx = blockIdx.x * 256 + threadIdx.x;
    if (idx >= K * N) return;
    const int k = idx / N;
    const int n = idx - k * N;
    const float w = W[idx];
    const __half hi = __float2half(w);
    const __half lo = __float2half((w - __half2float(hi)) * LO_SCALE);
    const int nt = n >> 4;
    const int kc = k >> 5;
    const int lane = ((k >> 3) & 3) * 16 + (n & 15);
    const int j = k & 7;
    const int KC = K >> 5;
    const size_t base = ((size_t)(nt * KC + kc) * 2) * 512 + lane * 8 + j;
    pack[base]       = __half_as_ushort(hi);
    pack[base + 512] = __half_as_ushort(lo);
}

// ---------------- pack Whh for the scan: wpk[(u*3+g)*1024 + j*4+q] = float4 --------
__global__ __launch_bounds__(256)
void pack_wsc(const float* __restrict__ W, float* __restrict__ wpk)
{
    const int idx = blockIdx.x * 256 + threadIdx.x;
    if (idx >= 768 * 256) return;
    const int row = idx >> 8;          // g*256 + j
    const int k   = idx & 255;
    const int g = row >> 8;
    const int j = row & 255;
    const int u = k >> 4;
    const int q = (k >> 2) & 3;
    const int e = k & 3;
    wpk[(((size_t)(u * 3 + g) * 1024) + (j << 2) + q) * 4 + e] = W[idx];
}

// ---------------- gi GEMM chunk (MFMA fp16-split): t-slice [t0, t0+128) ------------
__global__ __launch_bounds__(512)
void gi_gemm_c(const float* __restrict__ Cm, const unsigned short* __restrict__ pack,
               const float* __restrict__ bcomb, float* __restrict__ gi, int t0)
{
    const int tid = threadIdx.x;
    const int w = tid >> 6, l = tid & 63;
    const int l15 = l & 15, l4 = l >> 4;
    const int bgrp = blockIdx.x >> 1;
    const int half = blockIdx.x & 1;
    const size_t m0 = (size_t)bgrp * 256 + t0 + half * 64;
    const size_t o0 = (size_t)bgrp * 128 + half * 64;

    __shared__ unsigned short alds[2][64 * 256];

    {
        const int row = tid >> 3;
        const int seg = (tid & 7) * 32;
        const float4* src = (const float4*)(Cm + (m0 + row) * 256 + seg);
        const int sw = (row & 7) << 3;
#pragma unroll
        for (int i = 0; i < 8; ++i) {
            float4 v = src[i];
            float vv[4] = {v.x, v.y, v.z, v.w};
#pragma unroll
            for (int e = 0; e < 4; ++e) {
                const float x = vv[e];
                const __half hi = __float2half(x);
                const __half lo = __float2half((x - __half2float(hi)) * LO_SCALE);
                const int ad = (row << 8) + ((seg + i * 4 + e) ^ sw);
                alds[0][ad] = __half_as_ushort(hi);
                alds[1][ad] = __half_as_ushort(lo);
            }
        }
    }
    __syncthreads();

    const int mt = w >> 1, nh = w & 1;
    f32x4 acc[24];
#pragma unroll
    for (int i = 0; i < 24; ++i) acc[i] = (f32x4){0.f, 0.f, 0.f, 0.f};

    const int ar = mt * 16 + l15;
    const int arow = ar << 8;
    const int asw = (ar & 7) << 3;

#pragma unroll
    for (int kc = 0; kc < 8; ++kc) {
        const int ad = arow + ((kc * 32 + l4 * 8) ^ asw);
        const f16x8 ahi = *(const f16x8*)&alds[0][ad];
        const f16x8 alo = *(const f16x8*)&alds[1][ad];
#pragma unroll
        for (int nt = 0; nt < 24; ++nt) {
            const int nt_lin = nh * 24 + nt;
            const uint4* bp = (const uint4*)(pack + ((size_t)(nt_lin * 8 + kc) * 2) * 512);
            uint4 bh4 = bp[l];
            uint4 bl4 = bp[64 + l];
            const f16x8 Bhi = *reinterpret_cast<const f16x8*>(&bh4);
            const f16x8 Blo = *reinterpret_cast<const f16x8*>(&bl4);
            acc[nt] = MFMA16(ahi, Bhi, acc[nt]);
            f32x4 t2 = (f32x4){0.f, 0.f, 0.f, 0.f};
            t2 = MFMA16(ahi, Blo, t2);
            t2 = MFMA16(alo, Bhi, t2);
#pragma unroll
            for (int r = 0; r < 4; ++r) acc[nt][r] = fmaf(LO_INV, t2[r], acc[nt][r]);
        }
    }

#pragma unroll
    for (int nt = 0; nt < 24; ++nt) {
        const int n = (nh * 24 + nt) * 16 + l15;
        const float bb = bcomb[n];
#pragma unroll
        for (int r = 0; r < 4; ++r) {
            const size_t om = o0 + mt * 16 + l4 * 4 + r;
            __builtin_nontemporal_store(acc[nt][r] + bb, &gi[om * 768 + n]);
        }
    }
}

// ---------------- GRU scan v13: G=8, 64 blocks, asm-pipelined weight loads ---------
// Weights stream via inline-asm global_load_dwordx4 in 16 u-chunks with a rolling
// 2-chunk register window; counted s_waitcnt vmcnt(N) + sched_barrier(0) prevents
// the compiler from folding the pipeline (it cannot reorder FMAs across the sched
// barrier, and asm-defined registers force true in-flight loads). gi prefetched
// one step ahead (always 6 loads -> uniform vmcnt counts). h in LDS ping-pong.
#define GLOADX4(dst, ptr) \
    asm volatile("global_load_dwordx4 %0, %1, off" : "=v"(dst) : "v"(ptr) : "memory")

__device__ __forceinline__ void chunk_fma(const float (*hbp)[256], int q, int u,
                                          f32x4 wr, f32x4 wz, f32x4 wn,
                                          float* ar, float* az, float* an)
{
    const int ha = u * 16 + q * 4;
#pragma unroll
    for (int b = 0; b < 8; ++b) {
        const float4 hv = *(const float4*)&hbp[b][ha];
        ar[b] = fmaf(wr[0], hv.x, ar[b]); ar[b] = fmaf(wr[1], hv.y, ar[b]);
        ar[b] = fmaf(wr[2], hv.z, ar[b]); ar[b] = fmaf(wr[3], hv.w, ar[b]);
        az[b] = fmaf(wz[0], hv.x, az[b]); az[b] = fmaf(wz[1], hv.y, az[b]);
        az[b] = fmaf(wz[2], hv.z, az[b]); az[b] = fmaf(wz[3], hv.w, az[b]);
        an[b] = fmaf(wn[0], hv.x, an[b]); an[b] = fmaf(wn[1], hv.y, an[b]);
        an[b] = fmaf(wn[2], hv.z, an[b]); an[b] = fmaf(wn[3], hv.w, an[b]);
    }
}

#define SCHUNK(U, KN, WR, WZ, WN)                                              \
    asm volatile("s_waitcnt vmcnt(" #KN ")" ::: "memory");                     \
    __builtin_amdgcn_sched_barrier(0);                                         \
    chunk_fma(hbp, q, U, WR, WZ, WN, ar, az, an);                              \
    if ((U) + 2 < 16) {                                                        \
        GLOADX4(WR, wbase + (((U) + 2) * 3 + 0) * 1024);                       \
        GLOADX4(WZ, wbase + (((U) + 2) * 3 + 1) * 1024);                       \
        GLOADX4(WN, wbase + (((U) + 2) * 3 + 2) * 1024);                       \
    }

__global__ __launch_bounds__(1024) __attribute__((amdgpu_waves_per_eu(4, 4)))
void gru_scan_v13(const float* __restrict__ gi_fc, const float* __restrict__ gi_bc,
                  const float* __restrict__ wpk_f, const float* __restrict__ wpk_b,
                  const float* __restrict__ bhh_f, const float* __restrict__ bhh_b,
                  float* __restrict__ H, float* __restrict__ hstate, int phase)
{
    const int bid = blockIdx.x;                   // 0..63
    const int xcd = bid & 7;
    const int dir = xcd >> 2;
    const int grp = (bid >> 3) * 4 + (xcd & 3);   // 0..31
    const float* __restrict__ gi = dir ? gi_bc : gi_fc;
    const f32x4* __restrict__ wbase0 = (const f32x4*)(dir ? wpk_b : wpk_f);
    const float* __restrict__ bhh = dir ? bhh_b : bhh_f;
    const int b0 = grp * 8;
    const int t0 = dir ? (128 - phase * 128) : (phase * 128);

    const int tid = threadIdx.x;
    const int j = tid >> 2;    // unit 0..255
    const int q = tid & 3;     // k-quarter; owns batches q and q+4
    const int bA = q, bB = q + 4;
    const f32x4* wbase = wbase0 + tid;

    __shared__ float hb[2][8][256];

    float hregA, hregB;
    if (phase == 0) { hregA = 0.f; hregB = 0.f; }
    else {
        hregA = hstate[((size_t)dir * 256 + b0 + bA) * 256 + j];
        hregB = hstate[((size_t)dir * 256 + b0 + bB) * 256 + j];
    }
    hb[0][bA][j] = hregA;
    hb[0][bB][j] = hregB;

    const float bh_r = bhh[j], bh_z = bhh[j + 256], bh_n = bhh[j + 512];

    __syncthreads();

    // gi pipeline: prefetch step 0 for both owned batches
    const int sc00 = dir ? 127 : 0;
    const float* gA0 = gi + ((size_t)(b0 + bA) * 128 + sc00) * 768 + j;
    const float* gB0 = gi + ((size_t)(b0 + bB) * 128 + sc00) * 768 + j;
    float grA = __builtin_nontemporal_load(gA0);
    float gzA = __builtin_nontemporal_load(gA0 + 256);
    float gnA = __builtin_nontemporal_load(gA0 + 512);
    float grB = __builtin_nontemporal_load(gB0);
    float gzB = __builtin_nontemporal_load(gB0 + 256);
    float gnB = __builtin_nontemporal_load(gB0 + 512);

    int p = 0;
    for (int tau = 0; tau < 128; ++tau) {
        const int sc = dir ? (127 - tau) : tau;
        const int tt = t0 + sc;
        const float (*hbp)[256] = hb[p];

        const float g_rA = grA, g_zA = gzA, g_nA = gnA;
        const float g_rB = grB, g_zB = gzB, g_nB = gnB;

        // prologue: issue chunks 0 and 1 (asm, true in-flight loads)
        f32x4 wAr, wAz, wAn, wBr, wBz, wBn;
        GLOADX4(wAr, wbase + 0 * 1024);
        GLOADX4(wAz, wbase + 1 * 1024);
        GLOADX4(wAn, wbase + 2 * 1024);
        GLOADX4(wBr, wbase + 3 * 1024);
        GLOADX4(wBz, wbase + 4 * 1024);
        GLOADX4(wBn, wbase + 5 * 1024);

        // gi prefetch for next step (ALWAYS 6 loads -> uniform vmcnt counts)
        {
            const int scn = (tau < 127) ? (dir ? (126 - tau) : (tau + 1)) : sc;
            const float* gA = gi + ((size_t)(b0 + bA) * 128 + scn) * 768 + j;
            const float* gB = gi + ((size_t)(b0 + bB) * 128 + scn) * 768 + j;
            grA = __builtin_nontemporal_load(gA);
            gzA = __builtin_nontemporal_load(gA + 256);
            gnA = __builtin_nontemporal_load(gA + 512);
            grB = __builtin_nontemporal_load(gB);
            gzB = __builtin_nontemporal_load(gB + 256);
            gnB = __builtin_nontemporal_load(gB + 512);
        }

        float ar[8], az[8], an[8];
#pragma unroll
        for (int b = 0; b < 8; ++b) { ar[b] = 0.f; az[b] = 0.f; an[b] = 0.f; }

        // 16 chunks; waits: u<2 -> 9 younger (next chunk 3 + gi 6), u>=2 -> 3,
        // u==15 -> 0 (everything drained).
        SCHUNK(0, 9, wAr, wAz, wAn)
        SCHUNK(1, 9, wBr, wBz, wBn)
        SCHUNK(2, 3, wAr, wAz, wAn)
        SCHUNK(3, 3, wBr, wBz, wBn)
        SCHUNK(4, 3, wAr, wAz, wAn)
        SCHUNK(5, 3, wBr, wBz, wBn)
        SCHUNK(6, 3, wAr, wAz, wAn)
        SCHUNK(7, 3, wBr, wBz, wBn)
        SCHUNK(8, 3, wAr, wAz, wAn)
        SCHUNK(9, 3, wBr, wBz, wBn)
        SCHUNK(10, 3, wAr, wAz, wAn)
        SCHUNK(11, 3, wBr, wBz, wBn)
        SCHUNK(12, 3, wAr, wAz, wAn)
        SCHUNK(13, 3, wBr, wBz, wBn)
        SCHUNK(14, 3, wAr, wAz, wAn)
        SCHUNK(15, 0, wBr, wBz, wBn)

#pragma unroll
        for (int b = 0; b < 8; ++b) {
            ar[b] += __shfl_xor(ar[b], 1); ar[b] += __shfl_xor(ar[b], 2);
            az[b] += __shfl_xor(az[b], 1); az[b] += __shfl_xor(az[b], 2);
            an[b] += __shfl_xor(an[b], 1); an[b] += __shfl_xor(an[b], 2);
        }

        const float prA = (q == 0) ? ar[0] : (q == 1) ? ar[1] : (q == 2) ? ar[2] : ar[3];
        const float pzA = (q == 0) ? az[0] : (q == 1) ? az[1] : (q == 2) ? az[2] : az[3];
        const float pnA = (q == 0) ? an[0] : (q == 1) ? an[1] : (q == 2) ? an[2] : an[3];
        const float prB = (q == 0) ? ar[4] : (q == 1) ? ar[5] : (q == 2) ? ar[6] : ar[7];
        const float pzB = (q == 0) ? az[4] : (q == 1) ? az[5] : (q == 2) ? az[6] : az[7];
        const float pnB = (q == 0) ? an[4] : (q == 1) ? an[5] : (q == 2) ? an[6] : an[7];

        float rr = 1.0f / (1.0f + expf(-(g_rA + prA + bh_r)));
        float zz = 1.0f / (1.0f + expf(-(g_zA + pzA + bh_z)));
        float nn = tanhf(g_nA + rr * (pnA + bh_n));
        hregA = (1.0f - zz) * nn + zz * hregA;
        rr = 1.0f / (1.0f + expf(-(g_rB + prB + bh_r)));
        zz = 1.0f / (1.0f + expf(-(g_zB + pzB + bh_z)));
        nn = tanhf(g_nB + rr * (pnB + bh_n));
        hregB = (1.0f - zz) * nn + zz * hregB;

        hb[p ^ 1][bA][j] = hregA;
        hb[p ^ 1][bB][j] = hregB;
        __builtin_nontemporal_store(
            hregA, &H[((size_t)(b0 + bA) * 256 + tt) * 512 + dir * 256 + j]);
        __builtin_nontemporal_store(
            hregB, &H[((size_t)(b0 + bB) * 256 + tt) * 512 + dir * 256 + j]);
        __syncthreads();
        p ^= 1;
    }

    hstate[((size_t)dir * 256 + b0 + bA) * 256 + j] = hregA;
    hstate[((size_t)dir * 256 + b0 + bB) * 256 + j] = hregB;
}

// ---------------- row 1/max(norm,1e-12) for cosine normalization ------------------
__global__ __launch_bounds__(256)
void rownorm(const float* __restrict__ H, float* __restrict__ rinv)
{
    const int row  = blockIdx.x * 4 + (threadIdx.x >> 6);
    const int lane = threadIdx.x & 63;
    const float4* p = (const float4*)(H + (size_t)row * 512);
    float ss = 0.f;
    float4 v = p[lane];
    ss += v.x * v.x + v.y * v.y + v.z * v.z + v.w * v.w;
    v = p[lane + 64];
    ss += v.x * v.x + v.y * v.y + v.z * v.z + v.w * v.w;
#pragma unroll
    for (int off = 32; off >= 1; off >>= 1) ss += __shfl_xor(ss, off);
    if (lane == 0) rinv[row] = 1.0f / fmaxf(sqrtf(ss), 1e-12f);
}

// ---------------- sim (MFMA fp16-split, batched 256x256x512, rinv folded) ----------
__global__ __launch_bounds__(512)
void sim_mfma(const float* __restrict__ H, const float* __restrict__ rinv,
              float* __restrict__ sim)
{
    const int b = blockIdx.x;
    const int tid = threadIdx.x;
    const int w = tid >> 6, l = tid & 63;
    const int l15 = l & 15, l4 = l >> 4;

    __shared__ unsigned short st[2][256][40];

    f32x4 acc[2][16];
#pragma unroll
    for (int m = 0; m < 2; ++m)
#pragma unroll
        for (int n = 0; n < 16; ++n) acc[m][n] = (f32x4){0.f, 0.f, 0.f, 0.f};

    const int sr = tid >> 1;
    const int sh = (tid & 1) * 16;
    const float rv = rinv[b * 256 + sr];
    const float* hrow = H + ((size_t)b * 256 + sr) * 512;

    for (int kc = 0; kc < 16; ++kc) {
        if (kc) __syncthreads();
        {
            const float4* src = (const float4*)(hrow + kc * 32 + sh);
#pragma unroll
            for (int i = 0; i < 4; ++i) {
                float4 v = src[i];
                float vv[4] = {v.x, v.y, v.z, v.w};
                ushort4 h4, l4v;
                unsigned short* hp = (unsigned short*)&h4;
                unsigned short* lp = (unsigned short*)&l4v;
#pragma unroll
                for (int e = 0; e < 4; ++e) {
                    const float x = vv[e] * rv;
                    const __half hi = __float2half(x);
                    const __half lo = __float2half((x - __half2float(hi)) * LO_SCALE);
                    hp[e] = __half_as_ushort(hi);
                    lp[e] = __half_as_ushort(lo);
                }
                *(ushort4*)&st[0][sr][sh + i * 4] = h4;
                *(ushort4*)&st[1][sr][sh + i * 4] = l4v;
            }
        }
        __syncthreads();

        f16x8 ahi[2], alo[2];
#pragma unroll
        for (int m = 0; m < 2; ++m) {
            const int row = (w * 2 + m) * 16 + l15;
            ahi[m] = *(const f16x8*)&st[0][row][l4 * 8];
            alo[m] = *(const f16x8*)&st[1][row][l4 * 8];
        }
#pragma unroll
        for (int nt = 0; nt < 16; ++nt) {
            const int col = nt * 16 + l15;
            const f16x8 bhi = *(const f16x8*)&st[0][col][l4 * 8];
            const f16x8 blo = *(const f16x8*)&st[1][col][l4 * 8];
#pragma unroll
            for (int m = 0; m < 2; ++m) {
                acc[m][nt] = MFMA16(ahi[m], bhi, acc[m][nt]);
                f32x4 t2 = (f32x4){0.f, 0.f, 0.f, 0.f};
                t2 = MFMA16(ahi[m], blo, t2);
                t2 = MFMA16(alo[m], bhi, t2);
#pragma unroll
                for (int r = 0; r < 4; ++r)
                    acc[m][nt][r] = fmaf(LO_INV, t2[r], acc[m][nt][r]);
            }
        }
    }

#pragma unroll
    for (int m = 0; m < 2; ++m) {
        const int row0 = (w * 2 + m) * 16 + l4 * 4;
#pragma unroll
        for (int nt = 0; nt < 16; ++nt)
#pragma unroll
            for (int r = 0; r < 4; ++r)
                sim[((size_t)b * 256 + row0 + r) * 256 + nt * 16 + l15] = acc[m][nt][r];
    }
}

// ---------------- GCN layer GEMMs (MFMA fp16-split), A staged from fp32 ------------
template<int KDIM, int NDIM, int NT_PER>
__global__ __launch_bounds__(512)
void gcn_mm(const float* __restrict__ X, const unsigned short* __restrict__ pack,
            float* __restrict__ Y)
{
    const int tid = threadIdx.x;
    const int w = tid >> 6, l = tid & 63;
    const int l15 = l & 15, l4 = l >> 4;
    const int m0 = blockIdx.x * 64;
    constexpr int KC = KDIM / 32;

    __shared__ unsigned short a[2][64 * KDIM];

    {
        const int row = tid >> 3;
        const int seg = (tid & 7) * (KDIM / 8);
        const float4* src = (const float4*)(X + (size_t)(m0 + row) * KDIM + seg);
        const int sw = (row & 7) << 3;
#pragma unroll
        for (int i = 0; i < KDIM / 32; ++i) {
            float4 v = src[i];
            float vv[4] = {v.x, v.y, v.z, v.w};
#pragma unroll
            for (int e = 0; e < 4; ++e) {
                const float x = vv[e];
                const __half hi = __float2half(x);
                const __half lo = __float2half((x - __half2float(hi)) * LO_SCALE);
                const int ad = row * KDIM + ((seg + i * 4 + e) ^ sw);
                a[0][ad] = __half_as_ushort(hi);
                a[1][ad] = __half_as_ushort(lo);
            }
        }
    }
    __syncthreads();

    const int mt = w >> 1, nh = w & 1;
    f32x4 acc[NT_PER];
#pragma unroll
    for (int i = 0; i < NT_PER; ++i) acc[i] = (f32x4){0.f, 0.f, 0.f, 0.f};

    const int arow = mt * 16 + l15;
    const int abase = arow * KDIM;
    const int asw = (arow & 7) << 3;

#pragma unroll
    for (int kc = 0; kc < KC; ++kc) {
        const int ad = abase + ((kc * 32 + l4 * 8) ^ asw);
        const f16x8 ahi = *(const f16x8*)&a[0][ad];
        const f16x8 alo = *(const f16x8*)&a[1][ad];
#pragma unroll
        for (int ntl = 0; ntl < NT_PER; ++ntl) {
            const int nt = nh * NT_PER + ntl;
            const uint4* bp = (const uint4*)(pack + ((size_t)(nt * KC + kc) * 2) * 512);
            uint4 bh4 = bp[l];
            uint4 bl4 = bp[64 + l];
            const f16x8 Bhi = *reinterpret_cast<const f16x8*>(&bh4);
            const f16x8 Blo = *reinterpret_cast<const f16x8*>(&bl4);
            acc[ntl] = MFMA16(ahi, Bhi, acc[ntl]);
            f32x4 t2 = (f32x4){0.f, 0.f, 0.f, 0.f};
            t2 = MFMA16(ahi, Blo, t2);
            t2 = MFMA16(alo, Bhi, t2);
#pragma unroll
            for (int r = 0; r < 4; ++r) acc[ntl][r] = fmaf(LO_INV, t2[r], acc[ntl][r]);
        }
    }

#pragma unroll
    for (int ntl = 0; ntl < NT_PER; ++ntl) {
        const int n = (nh * NT_PER + ntl) * 16 + l15;
#pragma unroll
        for (int r = 0; r < 4; ++r) {
            const int m = m0 + mt * 16 + l4 * 4 + r;
            Y[(size_t)m * NDIM + n] = acc[ntl][r];
        }
    }
}

// ---------------- top-5 per sim row (strict >, jax lower-index tie behavior) ------
__global__ __launch_bounds__(256)
void topk5(const float* __restrict__ sim, int* __restrict__ idx)
{
    const int row = blockIdx.x * 256 + threadIdx.x;
    const float* p = sim + (size_t)row * 256;
    float bv0 = -1e30f, bv1 = -1e30f, bv2 = -1e30f, bv3 = -1e30f, bv4 = -1e30f;
    int   bi0 = 0, bi1 = 0, bi2 = 0, bi3 = 0, bi4 = 0;
    for (int m4 = 0; m4 < 64; ++m4) {
        float4 v4 = *(const float4*)(p + m4 * 4);
        float vv[4] = {v4.x, v4.y, v4.z, v4.w};
#pragma unroll
        for (int c = 0; c < 4; ++c) {
            float v = vv[c];
            int   m = m4 * 4 + c;
            if (v > bv0) {
                if (v > bv1) {
                    bv0 = bv1; bi0 = bi1;
                    if (v > bv2) {
                        bv1 = bv2; bi1 = bi2;
                        if (v > bv3) {
                            bv2 = bv3; bi2 = bi3;
                            if (v > bv4) { bv3 = bv4; bi3 = bi4; bv4 = v; bi4 = m; }
                            else         { bv3 = v;  bi3 = m; }
                        } else { bv2 = v; bi2 = m; }
                    } else { bv1 = v; bi1 = m; }
                } else { bv0 = v; bi0 = m; }
            }
        }
    }
    int* o = idx + (size_t)row * 5;
    o[0] = bi0; o[1] = bi1; o[2] = bi2; o[3] = bi3; o[4] = bi4;
}

// ---------------- sparse GCN aggregation: out[n] = c*(X[n] + sum_j X[idx_j]) ------
template<bool RELU, int DIM>
__global__ __launch_bounds__(128)
void gcn_agg(const float* __restrict__ X, const int* __restrict__ idxs,
             float* __restrict__ outp, float cnorm)
{
    const int row = blockIdx.x;
    const int bbase = row & ~255;
    const int* id = idxs + (size_t)row * 5;
    const int i0 = bbase + id[0];
    const int i1 = bbase + id[1];
    const int i2 = bbase + id[2];
    const int i3 = bbase + id[3];
    const int i4 = bbase + id[4];
    const int t = threadIdx.x;
    if (DIM == 512) {
        const float4* Xp = (const float4*)X;
        float4 a = Xp[(size_t)row * 128 + t];
        float4 v;
        v = Xp[(size_t)i0 * 128 + t]; a.x += v.x; a.y += v.y; a.z += v.z; a.w += v.w;
        v = Xp[(size_t)i1 * 128 + t]; a.x += v.x; a.y += v.y; a.z += v.z; a.w += v.w;
        v = Xp[(size_t)i2 * 128 + t]; a.x += v.x; a.y += v.y; a.z += v.z; a.w += v.w;
        v = Xp[(size_t)i3 * 128 + t]; a.x += v.x; a.y += v.y; a.z += v.z; a.w += v.w;
        v = Xp[(size_t)i4 * 128 + t]; a.x += v.x; a.y += v.y; a.z += v.z; a.w += v.w;
        a.x *= cnorm; a.y *= cnorm; a.z *= cnorm; a.w *= cnorm;
        if (RELU) {
            a.x = fmaxf(a.x, 0.f); a.y = fmaxf(a.y, 0.f);
            a.z = fmaxf(a.z, 0.f); a.w = fmaxf(a.w, 0.f);
        }
        ((float4*)outp)[(size_t)row * 128 + t] = a;
    } else {
        float a = X[(size_t)row * 128 + t];
        a += X[(size_t)i0 * 128 + t];
        a += X[(size_t)i1 * 128 + t];
        a += X[(size_t)i2 * 128 + t];
        a += X[(size_t)i3 * 128 + t];
        a += X[(size_t)i4 * 128 + t];
        a *= cnorm;
        if (RELU) a = fmaxf(a, 0.f);
        outp[(size_t)row * 128 + t] = a;
    }
}

// ------------------------------- launcher -----------------------------------------
extern "C" void kernel_launch(void* const* d_in, const int* in_sizes, int n_in,
                              void* d_out, int out_size, void* d_ws, size_t ws_size,
                              hipStream_t stream)
{
    (void)in_sizes; (void)n_in; (void)out_size; (void)ws_size;

    const float* C_masked = (const float*)d_in[0];
    const float* W_proj   = (const float*)d_in[1];
    const float* b_proj   = (const float*)d_in[2];
    const float* Wih_f    = (const float*)d_in[3];
    const float* Whh_f    = (const float*)d_in[4];
    const float* bih_f    = (const float*)d_in[5];
    const float* bhh_f    = (const float*)d_in[6];
    const float* Wih_b    = (const float*)d_in[7];
    const float* Whh_b    = (const float*)d_in[8];
    const float* bih_b    = (const float*)d_in[9];
    const float* bhh_b    = (const float*)d_in[10];
    const float* W_gcn1   = (const float*)d_in[11];
    const float* W_gcn2   = (const float*)d_in[12];
    float* out = (float*)d_out;

    char* ws = (char*)d_ws;
    size_t o = 0;
    auto take = [&](size_t bytes) {
        size_t r = o;
        o = (o + bytes + 255) & ~(size_t)255;
        return r;
    };
    const size_t WCOMB_B = (size_t)768 * 256 * 4;
    const size_t PACK_B  = (size_t)48 * 8 * 2 * 512 * 2;   // 786432
    const size_t PACKG_B = (size_t)262144;
    const size_t o_wcf  = take(WCOMB_B);
    const size_t o_wcb  = take(WCOMB_B);
    const size_t o_bcf  = take(768 * 4);
    const size_t o_bcb  = take(768 * 4);
    const size_t o_rinv = take((size_t)65536 * 4);
    const size_t o_topk = take((size_t)65536 * 5 * 4);
    const size_t o_pwf  = take(PACK_B);
    const size_t o_pwb  = take(PACK_B);
    const size_t o_wsf  = take(WCOMB_B);                   // scan weights fwd (packed)
    const size_t o_wsb  = take(WCOMB_B);                   // scan weights bwd (packed)
    const size_t o_pg1  = take(PACKG_B);
    const size_t o_pg2  = take(PACKG_B);
    const size_t o_hst  = take((size_t)512 * 256 * 4);     // h checkpoint (512 KB)
    const size_t regionA = o;

    const size_t GIC_BYTES = (size_t)256 * 128 * 768 * 4;  // 100.7 MB per dir
    // peak: regionA + 2*GIC + H ~= 343 MB

    float* wcomb_f = (float*)(ws + o_wcf);
    float* wcomb_b = (float*)(ws + o_wcb);
    float* bcomb_f = (float*)(ws + o_bcf);
    float* bcomb_b = (float*)(ws + o_bcb);
    float* rinv    = (float*)(ws + o_rinv);
    int*   topk    = (int*)(ws + o_topk);
    unsigned short* packWf = (unsigned short*)(ws + o_pwf);
    unsigned short* packWb = (unsigned short*)(ws + o_pwb);
    float* wpkF = (float*)(ws + o_wsf);
    float* wpkB = (float*)(ws + o_wsb);
    unsigned short* packG1 = (unsigned short*)(ws + o_pg1);
    unsigned short* packG2 = (unsigned short*)(ws + o_pg2);
    float* hstate = (float*)(ws + o_hst);

    float* gi_fc = (float*)(ws + regionA);
    float* gi_bc = (float*)(ws + regionA + GIC_BYTES);
    float* Hbuf  = (float*)(ws + regionA + 2 * GIC_BYTES);

    float* sim  = (float*)(ws + regionA);               // 67.1 MB
    float* XW1  = (float*)(ws + regionA + 67108864);    // 33.6 MB
    float* Z1   = (float*)(ws + regionA + 100663296);   // 33.6 MB
    float* Z1W2 = (float*)(ws + regionA);               // 134.2 MB

    const dim3 blk(256);

    // 1. combined weights + biases; packs
    gemm_f32<false><<<dim3(2, 6, 1), blk, 0, stream>>>(
        768, 256, 512, Wih_f, 0, W_proj, 0, wcomb_f, 0, nullptr, nullptr, nullptr);
    gemm_f32<false><<<dim3(2, 6, 1), blk, 0, stream>>>(
        768, 256, 512, Wih_b, 0, W_proj, 0, wcomb_b, 0, nullptr, nullptr, nullptr);
    bias_combine<<<3, 256, 0, stream>>>(Wih_f, b_proj, bih_f, bcomb_f);
    bias_combine<<<3, 256, 0, stream>>>(Wih_b, b_proj, bih_b, bcomb_b);
    pack_w<<<768, 256, 0, stream>>>(wcomb_f, packWf);
    pack_w<<<768, 256, 0, stream>>>(wcomb_b, packWb);
    pack_wsc<<<768, 256, 0, stream>>>(Whh_f, wpkF);
    pack_wsc<<<768, 256, 0, stream>>>(Whh_b, wpkB);
    pack_bk<<<256, 256, 0, stream>>>(W_gcn1, packG1, 512, 128);
    pack_bk<<<256, 256, 0, stream>>>(W_gcn2, packG2, 128, 512);

    // 2. time-chunked gi + bidirectional parallel scan (2 phases x 128 steps)
    gi_gemm_c<<<512, 512, 0, stream>>>(C_masked, packWf, bcomb_f, gi_fc, 0);
    gi_gemm_c<<<512, 512, 0, stream>>>(C_masked, packWb, bcomb_b, gi_bc, 128);
    gru_scan_v13<<<64, 1024, 0, stream>>>(gi_fc, gi_bc, wpkF, wpkB,
                                          bhh_f, bhh_b, Hbuf, hstate, 0);
    gi_gemm_c<<<512, 512, 0, stream>>>(C_masked, packWf, bcomb_f, gi_fc, 128);
    gi_gemm_c<<<512, 512, 0, stream>>>(C_masked, packWb, bcomb_b, gi_bc, 0);
    gru_scan_v13<<<64, 1024, 0, stream>>>(gi_fc, gi_bc, wpkF, wpkB,
                                          bhh_f, bhh_b, Hbuf, hstate, 1);

    // 3. cosine-sim (MFMA, rinv folded) -> top-5
    rownorm<<<16384, blk, 0, stream>>>(Hbuf, rinv);
    sim_mfma<<<256, 512, 0, stream>>>(Hbuf, rinv, sim);
    topk5<<<256, blk, 0, stream>>>(sim, topk);

    // 4. GCN with A_norm = A / (6 + 1e-8)  (row-sum of A is always K+1 = 6)
    const float cnorm = (float)(1.0 / (6.0 + 1e-8));
    gcn_mm<512, 128, 4><<<1024, 512, 0, stream>>>(Hbuf, packG1, XW1);
    gcn_agg<true, 128><<<65536, 128, 0, stream>>>(XW1, topk, Z1, cnorm);
    gcn_mm<128, 512, 16><<<1024, 512, 0, stream>>>(Z1, packG2, Z1W2);
    gcn_agg<false, 512><<<65536, 128, 0, stream>>>(Z1W2, topk, out, cnorm);
}